// Round 1
// baseline (896.599 us; speedup 1.0000x reference)
//
#include <hip/hip_runtime.h>
#include <math.h>

// Problem dims
#define NB 256
#define NT 512
#define NF 128
#define NCOH 64         // coh_pts
#define NIN 192         // F + coh_pts
#define NBS 384         // 3*bulk_pts
#define NROWS (NB*NT)   // 131072

// Material constants (match fp64->fp32 of reference)
#define C11 1098.9010989010989f
#define C12 329.67032967032966f
#define C33 384.61538461538464f
#define H3G 1253.8461538461538f   // 3*G + HARD

// ---------------------------------------------------------------------------
// K1: jumps = leaky_relu(x @ W11^T + b11); d_new from pairs. Tile 128x128, BK=16.
// ---------------------------------------------------------------------------
__global__ __launch_bounds__(256, 2) void k1_fc11(
    const float* __restrict__ x, const float* __restrict__ W11,
    const float* __restrict__ b11, float* __restrict__ dnew)
{
    __shared__ float As[16][132];
    __shared__ float Bs[16][128];
    const int tid = threadIdx.x;
    const int row0 = blockIdx.x * 128;
    const int tx = tid & 15, ty = tid >> 4;

    float acc[8][8];
#pragma unroll
    for (int i = 0; i < 8; ++i)
#pragma unroll
        for (int j = 0; j < 8; ++j) acc[i][j] = 0.0f;

    const int lr = tid >> 2;          // 0..63
    const int lk = (tid & 3) * 4;     // 0,4,8,12
    const int bn = tid >> 1;          // 0..127
    const int bk = (tid & 1) * 8;     // 0,8

    for (int kc = 0; kc < 8; ++kc) {
        const int k0 = kc * 16;
        float4 a0 = *(const float4*)(x + (size_t)(row0 + lr) * NF + k0 + lk);
        float4 a1 = *(const float4*)(x + (size_t)(row0 + lr + 64) * NF + k0 + lk);
        float4 w0 = *(const float4*)(W11 + (size_t)bn * NF + k0 + bk);
        float4 w1 = *(const float4*)(W11 + (size_t)bn * NF + k0 + bk + 4);
        __syncthreads();
        As[lk+0][lr] = a0.x; As[lk+1][lr] = a0.y; As[lk+2][lr] = a0.z; As[lk+3][lr] = a0.w;
        As[lk+0][lr+64] = a1.x; As[lk+1][lr+64] = a1.y; As[lk+2][lr+64] = a1.z; As[lk+3][lr+64] = a1.w;
        Bs[bk+0][bn] = w0.x; Bs[bk+1][bn] = w0.y; Bs[bk+2][bn] = w0.z; Bs[bk+3][bn] = w0.w;
        Bs[bk+4][bn] = w1.x; Bs[bk+5][bn] = w1.y; Bs[bk+6][bn] = w1.z; Bs[bk+7][bn] = w1.w;
        __syncthreads();
#pragma unroll
        for (int k = 0; k < 16; ++k) {
            float4 av0 = *(const float4*)&As[k][8*ty];
            float4 av1 = *(const float4*)&As[k][8*ty+4];
            float4 bv0 = *(const float4*)&Bs[k][8*tx];
            float4 bv1 = *(const float4*)&Bs[k][8*tx+4];
            float a[8] = {av0.x,av0.y,av0.z,av0.w,av1.x,av1.y,av1.z,av1.w};
            float b[8] = {bv0.x,bv0.y,bv0.z,bv0.w,bv1.x,bv1.y,bv1.z,bv1.w};
#pragma unroll
            for (int i = 0; i < 8; ++i)
#pragma unroll
                for (int j = 0; j < 8; ++j)
                    acc[i][j] = fmaf(a[i], b[j], acc[i][j]);
        }
    }

#pragma unroll
    for (int i = 0; i < 8; ++i) {
        const int row = row0 + 8*ty + i;
        float dnv[4];
#pragma unroll
        for (int jp = 0; jp < 4; ++jp) {
            float z0 = acc[i][2*jp]   + b11[8*tx + 2*jp];
            float z1 = acc[i][2*jp+1] + b11[8*tx + 2*jp+1];
            // jn = relu(leaky(z0)) == relu(z0); js = leaky(z1)
            float jn = fmaxf(z0, 0.0f);
            float js = (z1 > 0.0f) ? z1 : 0.01f * z1;
            float delta = sqrtf(jn*jn + js*js + 1e-12f);
            float dn = 0.1f * (delta - 0.01f) / (fmaxf(delta, 1e-12f) * 0.09f);
            dnv[jp] = fminf(fmaxf(dn, 0.0f), 1.0f);
        }
        float4 dv; dv.x = dnv[0]; dv.y = dnv[1]; dv.z = dnv[2]; dv.w = dnv[3];
        *(float4*)(dnew + (size_t)row * NCOH + 4*tx) = dv;
    }
}

// ---------------------------------------------------------------------------
// K2: in-place cumulative max over t per (b, coh) chain.
// ---------------------------------------------------------------------------
__global__ __launch_bounds__(256) void k2_cummax(float* __restrict__ d)
{
    const int g = blockIdx.x * 256 + threadIdx.x;  // 0..16383
    const int b = g >> 6, c = g & 63;
    float* p = d + (size_t)b * NT * NCOH + c;
    float m = 0.0f;
#pragma unroll 8
    for (int t = 0; t < NT; ++t) {
        float v = p[(size_t)t * NCOH];
        m = fmaxf(m, v);
        p[(size_t)t * NCOH] = m;
    }
}

// ---------------------------------------------------------------------------
// K3: strain = concat(x, dmg) @ W12^T -> sig buffer (raw strain, D applied in K4)
// Tile 128 rows x 128 cols of 384, BK=16, 12 chunks (8 from x, 4 from dmg).
// ---------------------------------------------------------------------------
__global__ __launch_bounds__(256, 2) void k3_fc12(
    const float* __restrict__ x, const float* __restrict__ dmg,
    const float* __restrict__ W12, float* __restrict__ sig)
{
    __shared__ float As[16][132];
    __shared__ float Bs[16][128];
    const int tid = threadIdx.x;
    const int row0 = blockIdx.x * 128;
    const int n0 = blockIdx.y * 128;
    const int tx = tid & 15, ty = tid >> 4;

    float acc[8][8];
#pragma unroll
    for (int i = 0; i < 8; ++i)
#pragma unroll
        for (int j = 0; j < 8; ++j) acc[i][j] = 0.0f;

    const int lr = tid >> 2;
    const int lk = (tid & 3) * 4;
    const int bn = tid >> 1;
    const int bk = (tid & 1) * 8;

    for (int kc = 0; kc < 12; ++kc) {
        const int k0 = kc * 16;
        float4 a0, a1;
        if (k0 < NF) {
            a0 = *(const float4*)(x + (size_t)(row0 + lr) * NF + k0 + lk);
            a1 = *(const float4*)(x + (size_t)(row0 + lr + 64) * NF + k0 + lk);
        } else {
            a0 = *(const float4*)(dmg + (size_t)(row0 + lr) * NCOH + (k0 - NF) + lk);
            a1 = *(const float4*)(dmg + (size_t)(row0 + lr + 64) * NCOH + (k0 - NF) + lk);
        }
        float4 w0 = *(const float4*)(W12 + (size_t)(n0 + bn) * NIN + k0 + bk);
        float4 w1 = *(const float4*)(W12 + (size_t)(n0 + bn) * NIN + k0 + bk + 4);
        __syncthreads();
        As[lk+0][lr] = a0.x; As[lk+1][lr] = a0.y; As[lk+2][lr] = a0.z; As[lk+3][lr] = a0.w;
        As[lk+0][lr+64] = a1.x; As[lk+1][lr+64] = a1.y; As[lk+2][lr+64] = a1.z; As[lk+3][lr+64] = a1.w;
        Bs[bk+0][bn] = w0.x; Bs[bk+1][bn] = w0.y; Bs[bk+2][bn] = w0.z; Bs[bk+3][bn] = w0.w;
        Bs[bk+4][bn] = w1.x; Bs[bk+5][bn] = w1.y; Bs[bk+6][bn] = w1.z; Bs[bk+7][bn] = w1.w;
        __syncthreads();
#pragma unroll
        for (int k = 0; k < 16; ++k) {
            float4 av0 = *(const float4*)&As[k][8*ty];
            float4 av1 = *(const float4*)&As[k][8*ty+4];
            float4 bv0 = *(const float4*)&Bs[k][8*tx];
            float4 bv1 = *(const float4*)&Bs[k][8*tx+4];
            float a[8] = {av0.x,av0.y,av0.z,av0.w,av1.x,av1.y,av1.z,av1.w};
            float b[8] = {bv0.x,bv0.y,bv0.z,bv0.w,bv1.x,bv1.y,bv1.z,bv1.w};
#pragma unroll
            for (int i = 0; i < 8; ++i)
#pragma unroll
                for (int j = 0; j < 8; ++j)
                    acc[i][j] = fmaf(a[i], b[j], acc[i][j]);
        }
    }

#pragma unroll
    for (int i = 0; i < 8; ++i) {
        const int row = row0 + 8*ty + i;
        float4 s0, s1;
        s0.x = acc[i][0]; s0.y = acc[i][1]; s0.z = acc[i][2]; s0.w = acc[i][3];
        s1.x = acc[i][4]; s1.y = acc[i][5]; s1.z = acc[i][6]; s1.w = acc[i][7];
        *(float4*)(sig + (size_t)row * NBS + n0 + 8*tx)     = s0;
        *(float4*)(sig + (size_t)row * NBS + n0 + 8*tx + 4) = s1;
    }
}

// ---------------------------------------------------------------------------
// K4: per (b, bulk_pt) chain: sig_tr = D @ strain, seq, radial return ep-scan,
// scale stress in place.
// ---------------------------------------------------------------------------
__global__ __launch_bounds__(256) void k4_plast(float* __restrict__ sig)
{
    const int g = blockIdx.x * 256 + threadIdx.x;  // 0..32767
    const int b = g >> 7, p = g & 127;
    float* s = sig + (size_t)b * NT * NBS + 3 * p;
    float ep = 0.0f;
#pragma unroll 4
    for (int t = 0; t < NT; ++t) {
        float* sp = s + (size_t)t * NBS;
        float exx = sp[0], eyy = sp[1], gxy = sp[2];
        float sxx = C11 * exx + C12 * eyy;
        float syy = C12 * exx + C11 * eyy;
        float txy = C33 * gxy;
        float seq = sqrtf(sxx*sxx - sxx*syy + syy*syy + 3.0f*txy*txy + 1e-12f);
        float fy = seq - (10.0f + 100.0f * ep);
        float dep = (fy > 0.0f) ? (fy / H3G) : 0.0f;
        ep += dep;
        float scale = (fy > 0.0f) ? ((10.0f + 100.0f * ep) / seq) : 1.0f;
        sp[0] = sxx * scale;
        sp[1] = syy * scale;
        sp[2] = txy * scale;
    }
}

// ---------------------------------------------------------------------------
// K5: out = softplus(sig @ W2^T), wave-per-row, W2 in LDS.
// ---------------------------------------------------------------------------
__global__ __launch_bounds__(256) void k5_out(
    const float* __restrict__ sig, const float* __restrict__ W2,
    float* __restrict__ out)
{
    __shared__ float W2s[6][NBS];
    const int tid = threadIdx.x;
    for (int i = tid; i < 6 * NBS; i += 256) W2s[i / NBS][i % NBS] = W2[i];
    __syncthreads();

    const int lane = tid & 63;
    const int wid = (blockIdx.x * 256 + tid) >> 6;
    const int nw = (gridDim.x * 256) >> 6;
    for (int row = wid; row < NROWS; row += nw) {
        const float* s = sig + (size_t)row * NBS;
        float acc[6] = {0,0,0,0,0,0};
#pragma unroll
        for (int kk = 0; kk < 6; ++kk) {
            float v = s[lane + 64*kk];
#pragma unroll
            for (int o = 0; o < 6; ++o) acc[o] = fmaf(v, W2s[o][lane + 64*kk], acc[o]);
        }
#pragma unroll
        for (int o = 0; o < 6; ++o) {
#pragma unroll
            for (int off = 32; off > 0; off >>= 1)
                acc[o] += __shfl_xor(acc[o], off);
        }
        if (lane == 0) {
#pragma unroll
            for (int o = 0; o < 6; ++o) {
                float z = acc[o];
                out[(size_t)row * 6 + o] = fmaxf(z, 0.0f) + log1pf(expf(-fabsf(z)));
            }
        }
    }
}

// ---------------------------------------------------------------------------
extern "C" void kernel_launch(void* const* d_in, const int* in_sizes, int n_in,
                              void* d_out, int out_size, void* d_ws, size_t ws_size,
                              hipStream_t stream)
{
    const float* x   = (const float*)d_in[0];
    const float* W11 = (const float*)d_in[1];
    const float* b11 = (const float*)d_in[2];
    const float* W12 = (const float*)d_in[3];
    const float* W2  = (const float*)d_in[4];
    float* out = (float*)d_out;

    // ws layout: dnew/dmg [NROWS*64] fp32 (32MB) | sig [NROWS*384] fp32 (192MB)
    float* dnew = (float*)d_ws;
    float* sig  = (float*)((char*)d_ws + (size_t)NROWS * NCOH * sizeof(float));

    k1_fc11<<<NROWS / 128, 256, 0, stream>>>(x, W11, b11, dnew);
    k2_cummax<<<(NB * NCOH) / 256, 256, 0, stream>>>(dnew);
    k3_fc12<<<dim3(NROWS / 128, 3), 256, 0, stream>>>(x, dnew, W12, sig);
    k4_plast<<<(NB * 128) / 256, 256, 0, stream>>>(sig);
    k5_out<<<1024, 256, 0, stream>>>(sig, W2, out);
}